// Round 10
// baseline (630.166 us; speedup 1.0000x reference)
//
#include <hip/hip_runtime.h>
#include <hip/hip_bf16.h>

// GRU-like fused cell: out = (1-z)*tanh(i_n + r*h_n) + z*e
// B=8, H=512, N=8192. bf16 MFMA 16x16x32, fp32 acc, fused epilogue.
//
// R9 -> R10: R5-R9 falsified regs/domains/depth/vmcnt/occupancy; the invariant
// is global_load_lds: LLVM can't alias-track LDS-DMA, so it forces
// s_waitcnt vmcnt(0) before every ds_read -> all prefetch drained per step.
// Also X loads were anti-coalesced (128KB lane stride) in all but R8.
// This round: pure reg-staging (precise per-reg waits, lgkm-only barriers),
// R8's coalesced X loads, and bank-floor b128 LDS writes:
//   A: addr = (tid*16)^(((tid>>3)&3)<<5), image unchanged (XORs cancel),
//      reads add ^((lane&3)<<5)
//   B: k-octet b128 writes, swizzle (((n>>1)&7)<<4)^(((n>>1)&3)<<5)

#define HH 512
#define NBATCH 8
#define NN 8192
#define BN 128
#define BK 64
#define NSTEPS 16
#define THREADS 256
#define A_BYTES (192 * BK * 2)          // 24576
#define B_BYTES (BN * BK * 2)           // 16384
#define BUF_BYTES (A_BYTES + B_BYTES)   // 40960
#define LDS_TOTAL (2 * BUF_BYTES)       // 81920 -> 2 WGs/CU

typedef __attribute__((ext_vector_type(8))) short short8;
typedef __attribute__((ext_vector_type(4))) float f32x4;

__device__ __forceinline__ unsigned cvt_pk_bf16(float a, float b) {
  unsigned r;
  asm("v_cvt_pk_bf16_f32 %0, %1, %2" : "=v"(r) : "v"(a), "v"(b));
  return r;
}

#define MFMA16(a_, b_, c_) __builtin_amdgcn_mfma_f32_16x16x32_bf16((a_), (b_), (c_), 0, 0, 0)

#define WG_BARRIER() do {                                   \
    asm volatile("s_waitcnt lgkmcnt(0)" ::: "memory");      \
    __builtin_amdgcn_sched_barrier(0);                      \
    __builtin_amdgcn_s_barrier();                           \
    __builtin_amdgcn_sched_barrier(0);                      \
  } while (0)

// ---------------- weight pre-pack (unchanged, verified R1-R9) ----------------
__global__ void prepack_w(const float* __restrict__ W_ih, const float* __restrict__ W_hh,
                          __hip_bfloat16* __restrict__ ws) {
  int t = blockIdx.x * 256 + threadIdx.x;
  int blk = t / 12288;                              // ht*16 + s
  int e = t % 12288;
  int ra = e >> 6;                                  // 0..191
  int kk = (e & 63) ^ ((ra & 7) << 3);              // inverse of read-side XOR swizzle
  int gate = ra >> 6;
  int h = (blk >> 4) * 64 + (ra & 63);
  int row = gate * HH + h;
  int kg = (blk & 15) * 64 + kk;
  float v = (kg < 512) ? W_ih[row * 512 + kg] : W_hh[row * 512 + (kg - 512)];
  ws[t] = __float2bfloat16(v);
}

// ---------------- main fused kernel ----------------
__global__ __launch_bounds__(THREADS, 2)
void gru_main(const float* __restrict__ e_wv, const float* __restrict__ m_wv,
              const __hip_bfloat16* __restrict__ wimg, float* __restrict__ out) {
  extern __shared__ char smem[];
  const int tid  = threadIdx.x;
  const int lane = tid & 63;
  const int wave = tid >> 6;       // 0..3
  const int wm = wave >> 1;        // 0..1 : 32-row half of 64-h tile
  const int wn = wave & 1;         // 0..1 : 64-col half of 128-n tile
  const int KW = wave << 4;        // 16 k-rows of X staged by this wave

  // XCD swizzle (bijective: 4096 % 8 == 0), ht fastest.
  const int wg  = blockIdx.x;
  const int swz = (wg & 7) * 512 + (wg >> 3);
  const int ht  = swz & 7;
  const int nt  = (swz >> 3) & 63;
  const int b   = swz >> 9;

  const size_t batch_off = (size_t)b * HH * NN;
  // coalesced X staging: per k-row, 64 lanes x float2 = 512B contiguous
  const float* xm = m_wv + batch_off + (size_t)KW * NN + nt * BN + 2 * lane;
  const float* xe = e_wv + batch_off + (size_t)KW * NN + nt * BN + 2 * lane;
  const char*  wA = (const char*)wimg + (size_t)ht * NSTEPS * A_BYTES;

  f32x4 acc_r[2][4]  = {};
  f32x4 acc_z[2][4]  = {};
  f32x4 acc_in[2][4] = {};
  f32x4 acc_hn[2][4] = {};

  uint4  aR[6];     // staged A image bytes (24 VGPR)
  float2 xR[16];    // staged X f32: 16 k-rows x cols (2*lane, 2*lane+1) (32 VGPR)

  // write-side constants
  const int awx  = ((tid >> 3) & 3) << 5;                       // A write XOR
  const int bswz = ((lane & 7) << 4) ^ ((lane & 3) << 5);       // B write swizzle (n>>1 = lane)

  // read-side offsets (lane-fixed swizzles; gate/mi/ni strides are immediates)
  const int swA = ((lane & 7) << 4) ^ ((lane & 3) << 5);
  const int swB = (((lane >> 1) & 7) << 4) ^ (((lane >> 1) & 3) << 5);
  int aoff[2], boff[2];
#pragma unroll
  for (int kb2 = 0; kb2 < 2; ++kb2) {
    const int ke2 = kb2 * 64 + ((lane >> 4) << 4);
    aoff[kb2] = (wm * 32 + (lane & 15)) * 128 + (ke2 ^ swA);
    boff[kb2] = A_BYTES + (wn * 64 + (lane & 15)) * 128 + (ke2 ^ swB);
  }

  auto issue_AX = [&](int t) {   // global -> regs, fully coalesced
    const char* gA = wA + (size_t)t * A_BYTES + tid * 16;
#pragma unroll
    for (int i = 0; i < 6; ++i)
      aR[i] = *(const uint4*)(gA + i * 4096);
    const float* xs = (t < 8 ? xm : xe) + (size_t)(t & 7) * (64 * NN);
#pragma unroll
    for (int i = 0; i < 16; ++i)
      xR[i] = *(const float2*)(xs + (size_t)i * NN);
  };

  auto write_AX = [&](char* nb) {  // regs -> LDS, all b128 at bank floor
    char* lA = nb + ((tid * 16) ^ awx);
#pragma unroll
    for (int i = 0; i < 6; ++i)
      *(uint4*)(lA + i * 4096) = aR[i];
    char* Bb = nb + A_BYTES + (2 * lane) * 128;
#pragma unroll
    for (int c = 0; c < 2; ++c) {
      uint4 w0, w1;
      w0.x = cvt_pk_bf16(xR[8 * c + 0].x, xR[8 * c + 1].x);
      w0.y = cvt_pk_bf16(xR[8 * c + 2].x, xR[8 * c + 3].x);
      w0.z = cvt_pk_bf16(xR[8 * c + 4].x, xR[8 * c + 5].x);
      w0.w = cvt_pk_bf16(xR[8 * c + 6].x, xR[8 * c + 7].x);
      w1.x = cvt_pk_bf16(xR[8 * c + 0].y, xR[8 * c + 1].y);
      w1.y = cvt_pk_bf16(xR[8 * c + 2].y, xR[8 * c + 3].y);
      w1.z = cvt_pk_bf16(xR[8 * c + 4].y, xR[8 * c + 5].y);
      w1.w = cvt_pk_bf16(xR[8 * c + 6].y, xR[8 * c + 7].y);
      const int xoff = ((KW * 2) | (c * 16)) ^ bswz;   // k-octet byte offset, swizzled
      *(uint4*)(Bb + xoff)       = w0;                 // row 2*lane
      *(uint4*)(Bb + 128 + xoff) = w1;                 // row 2*lane+1
    }
  };

  auto compute_kb2 = [&](const char* cb, int kb2, bool firstHalf) {
    short8 bfr[4];
#pragma unroll
    for (int ni = 0; ni < 4; ++ni)
      bfr[ni] = *(const short8*)(cb + boff[kb2] + ni * 2048);
    {  // gate r
      short8 a0 = *(const short8*)(cb + aoff[kb2]);
      short8 a1 = *(const short8*)(cb + aoff[kb2] + 2048);
#pragma unroll
      for (int ni = 0; ni < 4; ++ni) {
        acc_r[0][ni] = MFMA16(a0, bfr[ni], acc_r[0][ni]);
        acc_r[1][ni] = MFMA16(a1, bfr[ni], acc_r[1][ni]);
      }
    }
    {  // gate z
      short8 a0 = *(const short8*)(cb + aoff[kb2] + 8192);
      short8 a1 = *(const short8*)(cb + aoff[kb2] + 8192 + 2048);
#pragma unroll
      for (int ni = 0; ni < 4; ++ni) {
        acc_z[0][ni] = MFMA16(a0, bfr[ni], acc_z[0][ni]);
        acc_z[1][ni] = MFMA16(a1, bfr[ni], acc_z[1][ni]);
      }
    }
    {  // gate n -> acc_in (m-phase) / acc_hn (e-phase)
      short8 a0 = *(const short8*)(cb + aoff[kb2] + 16384);
      short8 a1 = *(const short8*)(cb + aoff[kb2] + 16384 + 2048);
      if (firstHalf) {
#pragma unroll
        for (int ni = 0; ni < 4; ++ni) {
          acc_in[0][ni] = MFMA16(a0, bfr[ni], acc_in[0][ni]);
          acc_in[1][ni] = MFMA16(a1, bfr[ni], acc_in[1][ni]);
        }
      } else {
#pragma unroll
        for (int ni = 0; ni < 4; ++ni) {
          acc_hn[0][ni] = MFMA16(a0, bfr[ni], acc_hn[0][ni]);
          acc_hn[1][ni] = MFMA16(a1, bfr[ni], acc_hn[1][ni]);
        }
      }
    }
  };

  // prologue: buf0 <- tile(0); tile(1) loads in flight across the barrier
  issue_AX(0);
  write_AX(smem);       // precise vmcnt waits on aR/xR here
  issue_AX(1);
  WG_BARRIER();         // lgkm only: tile(1) loads stay in flight

#pragma unroll 1
  for (int s = 0; s < NSTEPS; ++s) {
    char* cb = smem + ((s & 1) ? BUF_BYTES : 0);
    char* nb = smem + ((s & 1) ? 0 : BUF_BYTES);
    const bool firstHalf = (s < 8);

    if (s + 1 < NSTEPS) write_AX(nb);     // consume regs loaded one full step ago
    if (s + 2 < NSTEPS) issue_AX(s + 2);  // fly across compute + next write

    __builtin_amdgcn_s_setprio(1);
    compute_kb2(cb, 0, firstHalf);
    compute_kb2(cb, 1, firstHalf);
    __builtin_amdgcn_s_setprio(0);

    WG_BARRIER();                         // lgkm only: vm loads uninterrupted
  }

  // epilogue: gates + blend (unchanged, verified R1-R9)
  const size_t obase = batch_off + (size_t)(ht * 64 + wm * 32) * NN + nt * BN + wn * 64;
  const float* ep = e_wv + obase;
  float* op = out + obase;
  const int rsub = (lane >> 4) << 2;
  const int csub = lane & 15;
#pragma unroll
  for (int mi = 0; mi < 2; ++mi)
#pragma unroll
    for (int ni = 0; ni < 4; ++ni) {
#pragma unroll
      for (int r = 0; r < 4; ++r) {
        size_t idx = (size_t)(mi * 16 + rsub + r) * NN + ni * 16 + csub;
        float pr  = acc_r[mi][ni][r];
        float pz  = acc_z[mi][ni][r];
        float vin = acc_in[mi][ni][r];
        float vhn = acc_hn[mi][ni][r];
        float rr  = 1.f / (1.f + __expf(-pr));
        float zz  = 1.f / (1.f + __expf(-pz));
        float ex  = __expf(2.f * (vin + rr * vhn));
        float nn2 = 1.f - 2.f / (ex + 1.f);      // tanh, inf-safe
        float ev  = ep[idx];
        op[idx] = (1.f - zz) * nn2 + zz * ev;
      }
    }
}

extern "C" void kernel_launch(void* const* d_in, const int* in_sizes, int n_in,
                              void* d_out, int out_size, void* d_ws, size_t ws_size,
                              hipStream_t stream) {
  const float* e_wv = (const float*)d_in[0];
  const float* m_wv = (const float*)d_in[1];
  const float* W_ih = (const float*)d_in[2];
  const float* W_hh = (const float*)d_in[3];
  float* out = (float*)d_out;
  __hip_bfloat16* wimg = (__hip_bfloat16*)d_ws;   // 3 MiB weight image

  (void)hipFuncSetAttribute((const void*)gru_main,
                            hipFuncAttributeMaxDynamicSharedMemorySize, LDS_TOTAL);

  prepack_w<<<(NBATCH * NSTEPS * 12288) / 256, 256, 0, stream>>>(W_ih, W_hh, wimg);
  gru_main<<<NBATCH * 8 * 64, THREADS, LDS_TOTAL, stream>>>(e_wv, m_wv, wimg, out);
}

// Round 11
// 320.582 us; speedup vs baseline: 1.9657x; 1.9657x over previous
//
#include <hip/hip_runtime.h>
#include <hip/hip_bf16.h>

// GRU-like fused cell: out = (1-z)*tanh(i_n + r*h_n) + z*e
// B=8, H=512, N=8192. bf16 MFMA 16x16x32, fp32 acc, fused epilogue.
//
// R10 -> R11: reg-staging spills (R8/R10) => gload_lds A is mandatory at this
// acc count. R9 (2x waves, no change) implicates per-CU TA/transaction
// throughput: old X loads put lanes 16 rows apart -> ~16 transactions per
// instr. This round = R3's verified no-spill frame + WAVE-COALESCED X
// (per k-row, 64 lanes x float4 = 1KB contiguous) + B swizzle
// kbyte ^ ((n>>3&7)<<4) (write/read identical, b128 read at bank floor).

#define HH 512
#define NBATCH 8
#define NN 8192
#define BN 256
#define BK 64
#define NSTEPS 16
#define THREADS 512
#define A_BYTES (192 * BK * 2)          // 24576
#define B_BYTES (BN * 128)              // 32768
#define BUF_BYTES (A_BYTES + B_BYTES)   // 57344
#define LDS_TOTAL (2 * BUF_BYTES)       // 114688

typedef __attribute__((ext_vector_type(8))) short short8;
typedef __attribute__((ext_vector_type(4))) float f32x4;

__device__ __forceinline__ unsigned cvt_pk_bf16(float a, float b) {
  unsigned r;
  asm("v_cvt_pk_bf16_f32 %0, %1, %2" : "=v"(r) : "v"(a), "v"(b));
  return r;
}

__device__ __forceinline__ void gload_lds16(const void* g, void* l) {
  __builtin_amdgcn_global_load_lds(
      (__attribute__((address_space(1))) void*)(g),
      (__attribute__((address_space(3))) void*)(l), 16, 0, 0);
}

#define MFMA16(a_, b_, c_) __builtin_amdgcn_mfma_f32_16x16x32_bf16((a_), (b_), (c_), 0, 0, 0)

// ---------------- weight pre-pack (unchanged, verified R1-R10) ----------------
__global__ void prepack_w(const float* __restrict__ W_ih, const float* __restrict__ W_hh,
                          __hip_bfloat16* __restrict__ ws) {
  int t = blockIdx.x * 256 + threadIdx.x;
  int blk = t / 12288;                              // ht*16 + s
  int e = t % 12288;
  int ra = e >> 6;                                  // 0..191
  int kk = (e & 63) ^ ((ra & 7) << 3);              // inverse of read-side XOR swizzle
  int gate = ra >> 6;
  int h = (blk >> 4) * 64 + (ra & 63);
  int row = gate * HH + h;
  int kg = (blk & 15) * 64 + kk;
  float v = (kg < 512) ? W_ih[row * 512 + kg] : W_hh[row * 512 + (kg - 512)];
  ws[t] = __float2bfloat16(v);
}

// ---------------- main fused kernel ----------------
__global__ __launch_bounds__(THREADS, 2)
void gru_main(const float* __restrict__ e_wv, const float* __restrict__ m_wv,
              const __hip_bfloat16* __restrict__ wimg, float* __restrict__ out) {
  extern __shared__ char smem[];
  const int tid  = threadIdx.x;
  const int lane = tid & 63;
  const int wave = tid >> 6;       // 0..7
  const int wm = wave >> 2;        // 0..1 : 32-row half of 64-h tile
  const int wn = wave & 3;         // 0..3 : 64-col quarter of 256-n tile

  // XCD swizzle (bijective: 2048 % 8 == 0), ht fastest.
  const int wg  = blockIdx.x;
  const int swz = (wg & 7) * 256 + (wg >> 3);
  const int ht  = swz & 7;
  const int nt  = (swz >> 3) & 31;
  const int b   = swz >> 8;

  const size_t batch_off = (size_t)b * HH * NN;
  // Coalesced X staging: wave w owns k-rows [8w, 8w+8); per row, 64 lanes x
  // float4 = 1KB contiguous.
  const float* xm = m_wv + batch_off + (size_t)(8 * wave) * NN + nt * BN + 4 * lane;
  const float* xe = e_wv + batch_off + (size_t)(8 * wave) * NN + nt * BN + 4 * lane;
  const char*  wA = (const char*)wimg + (size_t)ht * NSTEPS * A_BYTES + tid * 16;

  f32x4 acc_r[2][4]  = {};
  f32x4 acc_z[2][4]  = {};
  f32x4 acc_in[2][4] = {};
  f32x4 acc_hn[2][4] = {};

  // A read offsets (R1-R10 verified: 128B rows, ^((lane&7)<<4), 0 conflicts)
  int aoff[2], boff[2];
  const int b3 = (lane >> 3) & 1;
#pragma unroll
  for (int kb2 = 0; kb2 < 2; ++kb2) {
    const int kb = kb2 * 64 + ((lane >> 4) << 4);
    aoff[kb2] = (wm * 32 + (lane & 15)) * 128 + (kb ^ ((lane & 7) << 4));
    // B: row n=wn*64+ni*16+(lane&15); swz=((n>>3)&7)<<4 = (ni<<5)|(b3<<4) ^ wn-part(=0 mod 8)
    boff[kb2] = A_BYTES + (wn * 64 + (lane & 15)) * 128 + (kb ^ (b3 << 4));
  }

  auto issue_A = [&](int s, char* nb) {
    const char* gA = wA + (size_t)s * A_BYTES;
    char* lA = nb + tid * 16;
    gload_lds16(gA,         lA);
    gload_lds16(gA + 8192,  lA + 8192);
    gload_lds16(gA + 16384, lA + 16384);
  };
  auto x_load_half = [&](const float* xs, int h, f32x4 c[4]) {
#pragma unroll
    for (int i = 0; i < 4; ++i)
      c[i] = *(const f32x4*)(xs + (size_t)(4 * h + i) * NN);
  };
  auto x_write_half = [&](char* nb, int h, const f32x4 c[4]) {
    // c[i][j] = X[k=8w+4h+i][n=4*lane+j] -> B[n][kbyte] with kbyte^((n>>3&7)<<4)
    char* Bb = nb + A_BYTES + (4 * lane) * 128;
    const int kh   = 16 * wave + 8 * h;          // base kbyte of this quad
    const int wswz = ((lane >> 1) & 7) << 4;     // (n>>3)&7 == (lane>>1)&7 for n=4l+j
#pragma unroll
    for (int j = 0; j < 4; ++j) {
      unsigned lo = cvt_pk_bf16(c[0][j], c[1][j]);   // k, k+1
      unsigned hi = cvt_pk_bf16(c[2][j], c[3][j]);   // k+2, k+3
      *(uint2*)(Bb + j * 128 + (kh ^ wswz)) = make_uint2(lo, hi);
    }
  };
  auto compute_kb2 = [&](const char* cb, int kb2, bool firstHalf) {
    short8 bfr[4];
#pragma unroll
    for (int ni = 0; ni < 4; ++ni)
      bfr[ni] = *(const short8*)(cb + ((boff[kb2] + ni * 2048) ^ (ni << 5)));
    {  // gate r
      short8 a0 = *(const short8*)(cb + aoff[kb2]);
      short8 a1 = *(const short8*)(cb + aoff[kb2] + 2048);
#pragma unroll
      for (int ni = 0; ni < 4; ++ni) {
        acc_r[0][ni] = MFMA16(a0, bfr[ni], acc_r[0][ni]);
        acc_r[1][ni] = MFMA16(a1, bfr[ni], acc_r[1][ni]);
      }
    }
    {  // gate z
      short8 a0 = *(const short8*)(cb + aoff[kb2] + 8192);
      short8 a1 = *(const short8*)(cb + aoff[kb2] + 8192 + 2048);
#pragma unroll
      for (int ni = 0; ni < 4; ++ni) {
        acc_z[0][ni] = MFMA16(a0, bfr[ni], acc_z[0][ni]);
        acc_z[1][ni] = MFMA16(a1, bfr[ni], acc_z[1][ni]);
      }
    }
    {  // gate n -> acc_in (m-phase) / acc_hn (e-phase)
      short8 a0 = *(const short8*)(cb + aoff[kb2] + 16384);
      short8 a1 = *(const short8*)(cb + aoff[kb2] + 16384 + 2048);
      if (firstHalf) {
#pragma unroll
        for (int ni = 0; ni < 4; ++ni) {
          acc_in[0][ni] = MFMA16(a0, bfr[ni], acc_in[0][ni]);
          acc_in[1][ni] = MFMA16(a1, bfr[ni], acc_in[1][ni]);
        }
      } else {
#pragma unroll
        for (int ni = 0; ni < 4; ++ni) {
          acc_hn[0][ni] = MFMA16(a0, bfr[ni], acc_hn[0][ni]);
          acc_hn[1][ni] = MFMA16(a1, bfr[ni], acc_hn[1][ni]);
        }
      }
    }
  };

  // prologue: stage step 0 into buf0
  issue_A(0, smem);
  {
    f32x4 c[4];
    x_load_half(xm, 0, c);
    x_write_half(smem, 0, c);
    x_load_half(xm, 1, c);
    x_write_half(smem, 1, c);
  }
  __syncthreads();

#pragma unroll 1
  for (int s = 0; s < NSTEPS; ++s) {
    char* cb = smem + ((s & 1) ? BUF_BYTES : 0);
    char* nb = smem + ((s & 1) ? 0 : BUF_BYTES);
    const bool pre = (s < NSTEPS - 1);
    const bool firstHalf = (s < 8);
    const float* xs = (s + 1 < 8 ? xm : xe) + (size_t)((s + 1) & 7) * (64 * NN);

    if (pre) issue_A(s + 1, nb);
    f32x4 c[4];
    if (pre) x_load_half(xs, 0, c);        // 4x 1KB-coalesced, in flight over compute0
    compute_kb2(cb, 0, firstHalf);
    if (pre) { x_write_half(nb, 0, c); x_load_half(xs, 1, c); }
    compute_kb2(cb, 1, firstHalf);
    if (pre) x_write_half(nb, 1, c);
    __syncthreads();
  }

  // epilogue: gates + blend (unchanged, verified R1-R10)
  const size_t obase = batch_off + (size_t)(ht * 64 + wm * 32) * NN + nt * BN + wn * 64;
  const float* ep = e_wv + obase;
  float* op = out + obase;
  const int rsub = (lane >> 4) << 2;
  const int csub = lane & 15;
#pragma unroll
  for (int mi = 0; mi < 2; ++mi)
#pragma unroll
    for (int ni = 0; ni < 4; ++ni) {
#pragma unroll
      for (int r = 0; r < 4; ++r) {
        size_t idx = (size_t)(mi * 16 + rsub + r) * NN + ni * 16 + csub;
        float pr  = acc_r[mi][ni][r];
        float pz  = acc_z[mi][ni][r];
        float vin = acc_in[mi][ni][r];
        float vhn = acc_hn[mi][ni][r];
        float rr  = 1.f / (1.f + __expf(-pr));
        float zz  = 1.f / (1.f + __expf(-pz));
        float ex  = __expf(2.f * (vin + rr * vhn));
        float nn2 = 1.f - 2.f / (ex + 1.f);      // tanh, inf-safe
        float ev  = ep[idx];
        op[idx] = (1.f - zz) * nn2 + zz * ev;
      }
    }
}

extern "C" void kernel_launch(void* const* d_in, const int* in_sizes, int n_in,
                              void* d_out, int out_size, void* d_ws, size_t ws_size,
                              hipStream_t stream) {
  const float* e_wv = (const float*)d_in[0];
  const float* m_wv = (const float*)d_in[1];
  const float* W_ih = (const float*)d_in[2];
  const float* W_hh = (const float*)d_in[3];
  float* out = (float*)d_out;
  __hip_bfloat16* wimg = (__hip_bfloat16*)d_ws;   // 3 MiB weight image

  (void)hipFuncSetAttribute((const void*)gru_main,
                            hipFuncAttributeMaxDynamicSharedMemorySize, LDS_TOTAL);

  prepack_w<<<(NBATCH * NSTEPS * 12288) / 256, 256, 0, stream>>>(W_ih, W_hh, wimg);
  gru_main<<<NBATCH * 8 * 32, THREADS, LDS_TOTAL, stream>>>(e_wv, m_wv, wimg, out);
}

// Round 12
// 317.242 us; speedup vs baseline: 1.9864x; 1.0105x over previous
//
#include <hip/hip_runtime.h>
#include <hip/hip_bf16.h>

// GRU-like fused cell: out = (1-z)*tanh(i_n + r*h_n) + z*e
// B=8, H=512, N=8192. bf16 MFMA 16x16x32, fp32 acc, fused epilogue.
//
// R11 -> R12: R11 confirmed transaction-coalescing (472->358) but its swizzle
// audit failed (3.35e7 conflicts: read lanes collapse to 4 slots = 16/bank) and
// it ran 1 WG/CU. R12 combines the two proven levers for the first time:
// R5 geometry (256thr, 2 WGs/CU = independent barrier domains) + coalesced X
// (wave owns 16 k-rows, per-row 64x float2 = 512B contiguous) + floor swizzle:
//   stored_byte = K ^ (((row>>1)&7)<<4), k-octet b128 writes
//   write: 8 slots x 8 lanes = 8/bank = b128 floor (0 conflicts)
//   read:  slots (l3, l5^l2, l4^l1) = 8 distinct x 8 lanes = floor
//   ni-stride stays +2048 (row>>1 & 7 invariant across ni,wn)

#define HH 512
#define NBATCH 8
#define NN 8192
#define BN 128
#define BK 64
#define NSTEPS 16
#define THREADS 256
#define A_BYTES (192 * BK * 2)          // 24576
#define B_BYTES (BN * 128)              // 16384
#define BUF_BYTES (A_BYTES + B_BYTES)   // 40960
#define LDS_TOTAL (2 * BUF_BYTES)       // 81920 -> 2 WGs/CU

typedef __attribute__((ext_vector_type(8))) short short8;
typedef __attribute__((ext_vector_type(4))) float f32x4;

__device__ __forceinline__ unsigned cvt_pk_bf16(float a, float b) {
  unsigned r;
  asm("v_cvt_pk_bf16_f32 %0, %1, %2" : "=v"(r) : "v"(a), "v"(b));
  return r;
}

__device__ __forceinline__ void gload_lds16(const void* g, void* l) {
  __builtin_amdgcn_global_load_lds(
      (__attribute__((address_space(1))) void*)(g),
      (__attribute__((address_space(3))) void*)(l), 16, 0, 0);
}

#define MFMA16(a_, b_, c_) __builtin_amdgcn_mfma_f32_16x16x32_bf16((a_), (b_), (c_), 0, 0, 0)

// ---------------- weight pre-pack (unchanged, verified R1-R11) ----------------
__global__ void prepack_w(const float* __restrict__ W_ih, const float* __restrict__ W_hh,
                          __hip_bfloat16* __restrict__ ws) {
  int t = blockIdx.x * 256 + threadIdx.x;
  int blk = t / 12288;                              // ht*16 + s
  int e = t % 12288;
  int ra = e >> 6;                                  // 0..191
  int kk = (e & 63) ^ ((ra & 7) << 3);              // inverse of read-side XOR swizzle
  int gate = ra >> 6;
  int h = (blk >> 4) * 64 + (ra & 63);
  int row = gate * HH + h;
  int kg = (blk & 15) * 64 + kk;
  float v = (kg < 512) ? W_ih[row * 512 + kg] : W_hh[row * 512 + (kg - 512)];
  ws[t] = __float2bfloat16(v);
}

// ---------------- main fused kernel ----------------
__global__ __launch_bounds__(THREADS, 2)
void gru_main(const float* __restrict__ e_wv, const float* __restrict__ m_wv,
              const __hip_bfloat16* __restrict__ wimg, float* __restrict__ out) {
  extern __shared__ char smem[];
  const int tid  = threadIdx.x;
  const int lane = tid & 63;
  const int wave = tid >> 6;       // 0..3
  const int wm = wave >> 1;        // 0..1 : 32-row half of 64-h tile
  const int wn = wave & 1;         // 0..1 : 64-col half of 128-n tile

  // XCD swizzle (bijective: 4096 % 8 == 0), ht fastest.
  const int wg  = blockIdx.x;
  const int swz = (wg & 7) * 512 + (wg >> 3);
  const int ht  = swz & 7;
  const int nt  = (swz >> 3) & 63;
  const int b   = swz >> 9;

  const size_t batch_off = (size_t)b * HH * NN;
  // Coalesced X: wave w owns k-rows [16w,16w+16); per row 64 lanes x float2.
  const float* xm = m_wv + batch_off + (size_t)(16 * wave) * NN + nt * BN + 2 * lane;
  const float* xe = e_wv + batch_off + (size_t)(16 * wave) * NN + nt * BN + 2 * lane;
  const char*  wA = (const char*)wimg + (size_t)ht * NSTEPS * A_BYTES + tid * 16;

  f32x4 acc_r[2][4]  = {};
  f32x4 acc_z[2][4]  = {};
  f32x4 acc_in[2][4] = {};
  f32x4 acc_hn[2][4] = {};
  float2 xR[16];   // transient staged X (32 VGPRs)

  // A read offsets (R1-R11 verified, 0 conflicts); B read = floor swizzle.
  int aoff[2], boff[2];
#pragma unroll
  for (int kb2 = 0; kb2 < 2; ++kb2) {
    const int K = kb2 * 64 + ((lane >> 4) << 4);
    aoff[kb2] = (wm * 32 + (lane & 15)) * 128 + (K ^ ((lane & 7) << 4));
    boff[kb2] = A_BYTES + (wn * 64 + (lane & 15)) * 128
              + (K ^ (((lane >> 1) & 7) << 4));
  }

  auto issue_A = [&](int s, char* nb) {
    const char* gA = wA + (size_t)s * A_BYTES;
    char* lA = nb + tid * 16;
#pragma unroll
    for (int i = 0; i < 6; ++i)
      gload_lds16(gA + i * 4096, lA + i * 4096);
  };
  auto x_load = [&](const float* xs) {
#pragma unroll
    for (int i = 0; i < 16; ++i)
      xR[i] = *(const float2*)(xs + (size_t)i * NN);
  };
  auto write_X = [&](char* nb) {
    // k-octet b128 writes: rows 2*lane, 2*lane+1; stored byte = K ^ ((lane&7)<<4)
    char* Bb = nb + A_BYTES + (2 * lane) * 128;
    const int sx = (lane & 7) << 4;
#pragma unroll
    for (int o = 0; o < 2; ++o) {
      uint4 w0, w1;
      w0.x = cvt_pk_bf16(xR[8 * o + 0].x, xR[8 * o + 1].x);
      w0.y = cvt_pk_bf16(xR[8 * o + 2].x, xR[8 * o + 3].x);
      w0.z = cvt_pk_bf16(xR[8 * o + 4].x, xR[8 * o + 5].x);
      w0.w = cvt_pk_bf16(xR[8 * o + 6].x, xR[8 * o + 7].x);
      w1.x = cvt_pk_bf16(xR[8 * o + 0].y, xR[8 * o + 1].y);
      w1.y = cvt_pk_bf16(xR[8 * o + 2].y, xR[8 * o + 3].y);
      w1.z = cvt_pk_bf16(xR[8 * o + 4].y, xR[8 * o + 5].y);
      w1.w = cvt_pk_bf16(xR[8 * o + 6].y, xR[8 * o + 7].y);
      const int kb = (32 * wave + 16 * o) ^ sx;
      *(uint4*)(Bb + kb)       = w0;   // row 2*lane
      *(uint4*)(Bb + 128 + kb) = w1;   // row 2*lane+1
    }
  };
  auto compute_kb2 = [&](const char* cb, int kb2, bool firstHalf) {
    short8 bfr[4];
#pragma unroll
    for (int ni = 0; ni < 4; ++ni)
      bfr[ni] = *(const short8*)(cb + boff[kb2] + ni * 2048);
    {  // gate r
      short8 a0 = *(const short8*)(cb + aoff[kb2]);
      short8 a1 = *(const short8*)(cb + aoff[kb2] + 2048);
#pragma unroll
      for (int ni = 0; ni < 4; ++ni) {
        acc_r[0][ni] = MFMA16(a0, bfr[ni], acc_r[0][ni]);
        acc_r[1][ni] = MFMA16(a1, bfr[ni], acc_r[1][ni]);
      }
    }
    {  // gate z
      short8 a0 = *(const short8*)(cb + aoff[kb2] + 8192);
      short8 a1 = *(const short8*)(cb + aoff[kb2] + 8192 + 2048);
#pragma unroll
      for (int ni = 0; ni < 4; ++ni) {
        acc_z[0][ni] = MFMA16(a0, bfr[ni], acc_z[0][ni]);
        acc_z[1][ni] = MFMA16(a1, bfr[ni], acc_z[1][ni]);
      }
    }
    {  // gate n -> acc_in (m-phase) / acc_hn (e-phase)
      short8 a0 = *(const short8*)(cb + aoff[kb2] + 16384);
      short8 a1 = *(const short8*)(cb + aoff[kb2] + 16384 + 2048);
      if (firstHalf) {
#pragma unroll
        for (int ni = 0; ni < 4; ++ni) {
          acc_in[0][ni] = MFMA16(a0, bfr[ni], acc_in[0][ni]);
          acc_in[1][ni] = MFMA16(a1, bfr[ni], acc_in[1][ni]);
        }
      } else {
#pragma unroll
        for (int ni = 0; ni < 4; ++ni) {
          acc_hn[0][ni] = MFMA16(a0, bfr[ni], acc_hn[0][ni]);
          acc_hn[1][ni] = MFMA16(a1, bfr[ni], acc_hn[1][ni]);
        }
      }
    }
  };

  // prologue: stage step 0 into buf0
  issue_A(0, smem);
  x_load(xm);
  write_X(smem);
  __syncthreads();

#pragma unroll 1
  for (int s = 0; s < NSTEPS; ++s) {
    char* cb = smem + ((s & 1) ? BUF_BYTES : 0);
    char* nb = smem + ((s & 1) ? 0 : BUF_BYTES);
    const bool pre = (s < NSTEPS - 1);
    const bool firstHalf = (s < 8);

    if (pre) {
      const int t = s + 1;
      x_load((t < 8 ? xm : xe) + (size_t)(t & 7) * (64 * NN));  // in flight over compute
      issue_A(t, nb);
    }
    __builtin_amdgcn_s_setprio(1);
    compute_kb2(cb, 0, firstHalf);
    compute_kb2(cb, 1, firstHalf);
    __builtin_amdgcn_s_setprio(0);
    if (pre) write_X(nb);
    __syncthreads();
  }

  // epilogue: gates + blend (unchanged, verified R1-R11)
  const size_t obase = batch_off + (size_t)(ht * 64 + wm * 32) * NN + nt * BN + wn * 64;
  const float* ep = e_wv + obase;
  float* op = out + obase;
  const int rsub = (lane >> 4) << 2;
  const int csub = lane & 15;
#pragma unroll
  for (int mi = 0; mi < 2; ++mi)
#pragma unroll
    for (int ni = 0; ni < 4; ++ni) {
#pragma unroll
      for (int r = 0; r < 4; ++r) {
        size_t idx = (size_t)(mi * 16 + rsub + r) * NN + ni * 16 + csub;
        float pr  = acc_r[mi][ni][r];
        float pz  = acc_z[mi][ni][r];
        float vin = acc_in[mi][ni][r];
        float vhn = acc_hn[mi][ni][r];
        float rr  = 1.f / (1.f + __expf(-pr));
        float zz  = 1.f / (1.f + __expf(-pz));
        float ex  = __expf(2.f * (vin + rr * vhn));
        float nn2 = 1.f - 2.f / (ex + 1.f);      // tanh, inf-safe
        float ev  = ep[idx];
        op[idx] = (1.f - zz) * nn2 + zz * ev;
      }
    }
}

extern "C" void kernel_launch(void* const* d_in, const int* in_sizes, int n_in,
                              void* d_out, int out_size, void* d_ws, size_t ws_size,
                              hipStream_t stream) {
  const float* e_wv = (const float*)d_in[0];
  const float* m_wv = (const float*)d_in[1];
  const float* W_ih = (const float*)d_in[2];
  const float* W_hh = (const float*)d_in[3];
  float* out = (float*)d_out;
  __hip_bfloat16* wimg = (__hip_bfloat16*)d_ws;   // 3 MiB weight image

  (void)hipFuncSetAttribute((const void*)gru_main,
                            hipFuncAttributeMaxDynamicSharedMemorySize, LDS_TOTAL);

  prepack_w<<<(NBATCH * NSTEPS * 12288) / 256, 256, 0, stream>>>(W_ih, W_hh, wimg);
  gru_main<<<NBATCH * 8 * 64, THREADS, LDS_TOTAL, stream>>>(e_wv, m_wv, wimg, out);
}